// Round 4
// baseline (297.081 us; speedup 1.0000x reference)
//
#include <hip/hip_runtime.h>
#include <stdint.h>

// Problem constants (reference: B,T,D=4,4096,1024; E,C,O=8,1024,512)
#define Bdim 4
#define Tdim 4096
#define Ddim 1024
#define Edim 8
#define Cdim 1024
#define Odim 512
#define KT 16  // K tiles of 64 (Ddim/64)

using bf16x8 = __attribute__((ext_vector_type(8))) __bf16;
using f32x4  = __attribute__((ext_vector_type(4))) float;

#define FENCE() asm volatile("" ::: "memory")
#define BAR()   do { FENCE(); __builtin_amdgcn_s_barrier(); FENCE(); } while (0)

// R8: FULLY FUSED gather+cast+GEMM (prep pass deleted — it was 28-46us of
// the 78-92us pipeline). Staging is T14 reg-staged: p0/p1 issue f32
// global_load_dwordx4 for tile t+1 -> VGPRs; p2/p3 cvt to bf16 + swizzled
// ds_write into the opposite LDS slot; lgkmcnt(0)+barrier publishes once
// per K-tile. Register-dest loads give the compiler an EXACT vmcnt
// scoreboard (no LDS-DMA alias conservatism, no manual vmcnt at all).
// Compute skeleton = R6 verbatim: 256x256 tile, 8 waves, 4 quadrant-phases
// per K-tile (16 MFMA each), T5 setprio, T2 XOR swizzle (now applied on the
// ds_write side), T1 XCD swizzle (e=bid&7), 8 static 16KiB LDS arrays,
// double-buffered E/O slots, identical read-side layout and epilogue.
__global__ __launch_bounds__(512) void moe_mfma_gemm(
    const float* __restrict__ x,      // (B,T,D) f32
    const int* __restrict__ idx,      // (B,E,C)
    const float* __restrict__ w,      // (E,O,D) f32
    const float* __restrict__ bias,   // (E,O)
    float* __restrict__ out) {        // (B,E,C,O) f32
  __shared__ __align__(16) unsigned short sA_e0[128 * 64];
  __shared__ __align__(16) unsigned short sA_e1[128 * 64];
  __shared__ __align__(16) unsigned short sA_o0[128 * 64];
  __shared__ __align__(16) unsigned short sA_o1[128 * 64];
  __shared__ __align__(16) unsigned short sB_e0[128 * 64];
  __shared__ __align__(16) unsigned short sB_e1[128 * 64];
  __shared__ __align__(16) unsigned short sB_o0[128 * 64];
  __shared__ __align__(16) unsigned short sB_o1[128 * 64];

  // XCD-aware decode: e fastest (XCD = e). 256 blocks = 1/CU.
  const int bid = blockIdx.x;
  const int e   = bid & 7;
  const int rr_ = bid >> 3;       // 0..31
  const int nt  = rr_ & 1;        // N tile (256 cols)
  const int mt  = (rr_ >> 1) & 3; // M tile (256 rows)
  const int bb  = rr_ >> 3;       // batch
  const int be  = bb * Edim + e;

  const int tid  = threadIdx.x;
  const int lane = tid & 63;
  const int wid  = tid >> 6;   // 0..7
  const int rw   = wid >> 2;   // 0..1: 64-row sub-block within the A half
  const int cw   = wid & 3;    // 0..3: 32-col sub-block within the B half

  // ---- staging geometry: wave covers rows wid*16..+15 of each 128-row
  // half; lane owns row rloc = wid*16 + (lane>>2) and the contiguous 16-f32
  // run at elems (lane&3)*16.. of the 64-wide K-tile (4x dwordx4, 64B).
  // After cvt: 16 bf16 = chunks c0=(lane&3)*2, c0+1; ds_write at chunk
  // (c ^ (rloc&7)) — same LDS image as R6/R7's pre-swizzle.
  const int rloc = wid * 16 + (lane >> 2);   // 0..127
  const int csub = (lane & 3) * 16;          // f32 elem offset in K-tile row

  const float4* aP4[2];
#pragma unroll
  for (int h = 0; h < 2; ++h) {
    const int tok = idx[be * Cdim + mt * 256 + h * 128 + rloc];
    aP4[h] = reinterpret_cast<const float4*>(
        x + (size_t)(bb * Tdim + tok) * Ddim + csub);
  }
  const float4* bP4[2];
#pragma unroll
  for (int h = 0; h < 2; ++h)
    bP4[h] = reinterpret_cast<const float4*>(
        w + (size_t)(e * Odim + nt * 256 + h * 128 + rloc) * Ddim + csub);

  const int wr0 = rloc * 64 + (((lane & 3) * 2) ^ (rloc & 7)) * 8;      // lo chunk
  const int wr1 = rloc * 64 + (((lane & 3) * 2 + 1) ^ (rloc & 7)) * 8;  // hi chunk

  float4 vA[2][4], vB[2][4];

#define ISSUE_A(t) do {                                                      \
    _Pragma("unroll")                                                        \
    for (int h = 0; h < 2; ++h)                                              \
      _Pragma("unroll")                                                      \
      for (int i = 0; i < 4; ++i) vA[h][i] = aP4[h][(t) * 16 + i];           \
  } while (0)
#define ISSUE_B(t) do {                                                      \
    _Pragma("unroll")                                                        \
    for (int h = 0; h < 2; ++h)                                              \
      _Pragma("unroll")                                                      \
      for (int i = 0; i < 4; ++i) vB[h][i] = bP4[h][(t) * 16 + i];           \
  } while (0)
#define CVT_WRITE(vreg, arr) do {                                            \
    bf16x8 lo, hi;                                                           \
    lo[0] = (__bf16)vreg[0].x; lo[1] = (__bf16)vreg[0].y;                    \
    lo[2] = (__bf16)vreg[0].z; lo[3] = (__bf16)vreg[0].w;                    \
    lo[4] = (__bf16)vreg[1].x; lo[5] = (__bf16)vreg[1].y;                    \
    lo[6] = (__bf16)vreg[1].z; lo[7] = (__bf16)vreg[1].w;                    \
    hi[0] = (__bf16)vreg[2].x; hi[1] = (__bf16)vreg[2].y;                    \
    hi[2] = (__bf16)vreg[2].z; hi[3] = (__bf16)vreg[2].w;                    \
    hi[4] = (__bf16)vreg[3].x; hi[5] = (__bf16)vreg[3].y;                    \
    hi[6] = (__bf16)vreg[3].z; hi[7] = (__bf16)vreg[3].w;                    \
    *reinterpret_cast<bf16x8*>(&arr[wr0]) = lo;                              \
    *reinterpret_cast<bf16x8*>(&arr[wr1]) = hi;                              \
  } while (0)
#define WR_A(arr0, arr1) do { CVT_WRITE(vA[0], arr0); CVT_WRITE(vA[1], arr1); } while (0)
#define WR_B(arr0, arr1) do { CVT_WRITE(vB[0], arr0); CVT_WRITE(vB[1], arr1); } while (0)

  // ---- prologue: stage tile 0 into the E slot (one exposed load latency)
  ISSUE_A(0);
  ISSUE_B(0);
  WR_A(sA_e0, sA_e1);
  WR_B(sB_e0, sB_e1);
  asm volatile("s_waitcnt lgkmcnt(0)" ::: "memory");
  BAR();

  const int fr  = lane & 15;   // fragment m/n index
  const int fkc = lane >> 4;   // fragment k-chunk (0..3)
  const int sw  = fr & 7;      // read-side XOR (== row&7)

  f32x4 acc[2][2][4][2];
#pragma unroll
  for (int a = 0; a < 2; ++a)
#pragma unroll
    for (int bq = 0; bq < 2; ++bq)
#pragma unroll
      for (int im = 0; im < 4; ++im)
#pragma unroll
        for (int in = 0; in < 2; ++in)
          acc[a][bq][im][in] = (f32x4){0.f, 0.f, 0.f, 0.f};

  bf16x8 af[4][2], bf0[2][2], bf1[2][2];

#define LD_A(arr)                                                            \
  _Pragma("unroll")                                                          \
  for (int im = 0; im < 4; ++im)                                             \
    _Pragma("unroll")                                                        \
    for (int kk = 0; kk < 2; ++kk)                                           \
      af[im][kk] = *(const bf16x8*)&arr[(size_t)(rw * 64 + im * 16 + fr) * 64 \
                                        + (((kk * 4 + fkc) ^ sw) * 8)];
#define LD_B(arr, dst)                                                       \
  _Pragma("unroll")                                                          \
  for (int in = 0; in < 2; ++in)                                             \
    _Pragma("unroll")                                                        \
    for (int kk = 0; kk < 2; ++kk)                                           \
      dst[in][kk] = *(const bf16x8*)&arr[(size_t)(cw * 32 + in * 16 + fr) * 64 \
                                         + (((kk * 4 + fkc) ^ sw) * 8)];
#define MFMA16(aq, bq_, B_)                                                  \
  __builtin_amdgcn_s_setprio(1);                                             \
  _Pragma("unroll")                                                          \
  for (int im = 0; im < 4; ++im)                                             \
    _Pragma("unroll")                                                        \
    for (int in = 0; in < 2; ++in)                                           \
      _Pragma("unroll")                                                      \
      for (int kk = 0; kk < 2; ++kk)                                         \
        acc[aq][bq_][im][in] = __builtin_amdgcn_mfma_f32_16x16x32_bf16(      \
            af[im][kk], B_[in][kk], acc[aq][bq_][im][in], 0, 0, 0);          \
  __builtin_amdgcn_s_setprio(0);

  for (int it = 0; it < KT / 2; ++it) {
    const bool g = (it < 7);

    // ================= even tile t = 2*it (E slot); stage t+1 -> O ======
    // p0: quadrant (0,0); issue A(t+1) loads
    LD_A(sA_e0);
    LD_B(sB_e0, bf0);
    ISSUE_A(2 * it + 1);
    BAR();
    MFMA16(0, 0, bf0);
    BAR();
    // p1: quadrant (0,1); issue B(t+1) loads
    LD_B(sB_e1, bf1);
    ISSUE_B(2 * it + 1);
    BAR();
    MFMA16(0, 1, bf1);
    BAR();
    // p2: quadrant (1,1); cvt+write A(t+1) (loads landed ~2 phases ago)
    LD_A(sA_e1);
    WR_A(sA_o0, sA_o1);
    BAR();
    MFMA16(1, 1, bf1);
    BAR();
    // p3: quadrant (1,0); cvt+write B(t+1); publish
    WR_B(sB_o0, sB_o1);
    BAR();
    MFMA16(1, 0, bf0);
    asm volatile("s_waitcnt lgkmcnt(0)" ::: "memory");
    BAR();

    // ================= odd tile t = 2*it+1 (O slot); stage t+1 -> E =====
    // p0: quadrant (0,0)
    LD_A(sA_o0);
    LD_B(sB_o0, bf0);
    if (g) ISSUE_A(2 * it + 2);
    BAR();
    MFMA16(0, 0, bf0);
    BAR();
    // p1: quadrant (0,1)
    LD_B(sB_o1, bf1);
    if (g) ISSUE_B(2 * it + 2);
    BAR();
    MFMA16(0, 1, bf1);
    BAR();
    // p2: quadrant (1,1)
    LD_A(sA_o1);
    if (g) WR_A(sA_e0, sA_e1);
    BAR();
    MFMA16(1, 1, bf1);
    BAR();
    // p3: quadrant (1,0); publish
    if (g) WR_B(sB_e0, sB_e1);
    BAR();
    MFMA16(1, 0, bf0);
    asm volatile("s_waitcnt lgkmcnt(0)" ::: "memory");
    BAR();
  }
#undef ISSUE_A
#undef ISSUE_B
#undef CVT_WRITE
#undef WR_A
#undef WR_B
#undef LD_A
#undef LD_B
#undef MFMA16

  // Epilogue. C/D layout (verified m89/m91): col = lane&15, row = (lane>>4)*4 + reg.
  const int crow0 = (lane >> 4) * 4;
  float* outBase = out + (size_t)be * (Cdim * Odim)
                 + (size_t)(mt * 256) * Odim + nt * 256;
#pragma unroll
  for (int a = 0; a < 2; ++a)
#pragma unroll
    for (int im = 0; im < 4; ++im) {
      float* prow = outBase + (size_t)(a * 128 + rw * 64 + im * 16 + crow0) * Odim;
#pragma unroll
      for (int bq = 0; bq < 2; ++bq)
#pragma unroll
        for (int in = 0; in < 2; ++in) {
          const int col  = bq * 128 + cw * 32 + in * 16 + fr;
          const float bv = bias[e * Odim + nt * 256 + col];
          float* p = prow + col;
#pragma unroll
          for (int r4 = 0; r4 < 4; ++r4)
            p[(size_t)r4 * Odim] = acc[a][bq][im][in][r4] + bv;
        }
    }
}

extern "C" void kernel_launch(void* const* d_in, const int* in_sizes, int n_in,
                              void* d_out, int out_size, void* d_ws, size_t ws_size,
                              hipStream_t stream) {
  const float* x = (const float*)d_in[0];       // (B,T,D) f32
  const int* idx = (const int*)d_in[1];         // (B,E,C) i32
  const float* w = (const float*)d_in[2];       // (E,O,D) f32
  const float* bias = (const float*)d_in[3];    // (E,O) f32
  float* out = (float*)d_out;
  (void)d_ws; (void)ws_size;  // fused kernel needs no workspace

  // 32 (b,e) pairs x 4 M-tiles x 2 N-tiles = 256 blocks (1/CU), XCD-swizzled
  moe_mfma_gemm<<<256, 512, 0, stream>>>(x, idx, w, bias, out);
}

// Round 5
// 207.149 us; speedup vs baseline: 1.4341x; 1.4341x over previous
//
#include <hip/hip_runtime.h>
#include <stdint.h>

// Problem constants (reference: B,T,D=4,4096,1024; E,C,O=8,1024,512)
#define Bdim 4
#define Tdim 4096
#define Ddim 1024
#define Edim 8
#define Cdim 1024
#define Odim 512
#define KT 16  // K tiles of 64 (Ddim/64)

using bf16x8 = __attribute__((ext_vector_type(8))) __bf16;
using f32x4  = __attribute__((ext_vector_type(4))) float;

// round-to-nearest-even f32 -> bf16
__device__ __forceinline__ unsigned short f2bf(float f) {
  unsigned int u = __float_as_uint(f);
  u += 0x7fffu + ((u >> 16) & 1u);
  return (unsigned short)(u >> 16);
}

// Tiny prep: cast ONLY the weights (E,O,D) f32->bf16, linear. ~24MB traffic.
__global__ void cast_w(const float* __restrict__ win,
                       unsigned short* __restrict__ outp, int n4) {
  int i = blockIdx.x * blockDim.x + threadIdx.x;
  if (i >= n4) return;
  float4 v = reinterpret_cast<const float4*>(win)[i];
  ushort4 o;
  o.x = f2bf(v.x); o.y = f2bf(v.y); o.z = f2bf(v.z); o.w = f2bf(v.w);
  reinterpret_cast<ushort4*>(outp)[i] = o;
}

#define FENCE() asm volatile("" ::: "memory")
#define BAR()   do { FENCE(); __builtin_amdgcn_s_barrier(); FENCE(); } while (0)

// R9: fused gather+cast GEMM, spill-fixed (R8 failure = compiler capped arch
// VGPR at 128 and spilled 226MB to scratch).
//  - __launch_bounds__(512,2): allow ~256 arch VGPR (2 waves/EU is what we
//    run anyway at 1 block/CU).
//  - B reg-staged as BF16 from a pre-cast wbf (16 VGPR, no cvt) — W cast
//    pass is only ~4-5us vs 28-46us for the old full prep.
//  - A reg-staged f32 gather + cvt (32 VGPR) — x read as f32; 64MB fits L3.
//  - Fragment-reload: bf0 reloaded from LDS at p3 instead of held p0->p3
//    (+4 ds_read_b128/tile, peak frag regs 96->64).
// Budget: acc 128 (AGPR) + staging 48 + frags 64 + addr ~20 ≈ 132 arch.
// NO LDS-DMA anywhere -> compiler waitcnt scoreboard exact, no manual vmcnt.
// Skeleton otherwise = R6: 256x256 tile, 8 waves, 4 quadrant-phases/K-tile,
// T5 setprio, T2 XOR swizzle (write-side), T1 XCD swizzle, 8 static LDS
// arrays double-buffered E/O.
__global__ __launch_bounds__(512, 2) void moe_mfma_gemm(
    const float* __restrict__ x,             // (B,T,D) f32
    const int* __restrict__ idx,             // (B,E,C)
    const unsigned short* __restrict__ wbf,  // (E,O,D) bf16 (pre-cast)
    const float* __restrict__ bias,          // (E,O)
    float* __restrict__ out) {               // (B,E,C,O) f32
  __shared__ __align__(16) unsigned short sA_e0[128 * 64];
  __shared__ __align__(16) unsigned short sA_e1[128 * 64];
  __shared__ __align__(16) unsigned short sA_o0[128 * 64];
  __shared__ __align__(16) unsigned short sA_o1[128 * 64];
  __shared__ __align__(16) unsigned short sB_e0[128 * 64];
  __shared__ __align__(16) unsigned short sB_e1[128 * 64];
  __shared__ __align__(16) unsigned short sB_o0[128 * 64];
  __shared__ __align__(16) unsigned short sB_o1[128 * 64];

  // XCD-aware decode: e fastest (XCD = e). 256 blocks = 1/CU.
  const int bid = blockIdx.x;
  const int e   = bid & 7;
  const int rr_ = bid >> 3;       // 0..31
  const int nt  = rr_ & 1;        // N tile (256 cols)
  const int mt  = (rr_ >> 1) & 3; // M tile (256 rows)
  const int bb  = rr_ >> 3;       // batch
  const int be  = bb * Edim + e;

  const int tid  = threadIdx.x;
  const int lane = tid & 63;
  const int wid  = tid >> 6;   // 0..7
  const int rw   = wid >> 2;   // 0..1: 64-row sub-block within the A half
  const int cw   = wid & 3;    // 0..3: 32-col sub-block within the B half

  // ---- staging geometry (identical for A and B): wave covers rows
  // wid*16..+15 of each 128-row half; lane owns row rloc = wid*16+(lane>>2)
  // and k-elems [(lane&3)*16, +16) of the 64-wide K-tile.
  // A: 16 f32 = 4 dwordx4 per half (32 VGPR both halves), cvt -> 2 chunks.
  // B: 16 bf16 = 2 dwordx4 per half (16 VGPR both halves), no cvt.
  // ds_write chunks c0=(lane&3)*2, c0+1 at (c ^ (rloc&7)) — same LDS image
  // as R6/R7.
  const int rloc = wid * 16 + (lane >> 2);   // 0..127
  const int csub = (lane & 3) * 16;          // elem offset in K-tile row

  const float4* aP4[2];
#pragma unroll
  for (int h = 0; h < 2; ++h) {
    const int tok = idx[be * Cdim + mt * 256 + h * 128 + rloc];
    aP4[h] = reinterpret_cast<const float4*>(
        x + (size_t)(bb * Tdim + tok) * Ddim + csub);
  }
  const uint4* bP4[2];
#pragma unroll
  for (int h = 0; h < 2; ++h)
    bP4[h] = reinterpret_cast<const uint4*>(
                 wbf + (size_t)(e * Odim + nt * 256 + h * 128 + rloc) * Ddim) +
             (lane & 3) * 2;

  const int wr0 = rloc * 64 + (((lane & 3) * 2) ^ (rloc & 7)) * 8;      // lo chunk
  const int wr1 = rloc * 64 + (((lane & 3) * 2 + 1) ^ (rloc & 7)) * 8;  // hi chunk

  float4 vA[2][4];
  uint4  vB[2][2];

#define ISSUE_A(t) do {                                                      \
    _Pragma("unroll")                                                        \
    for (int h = 0; h < 2; ++h)                                              \
      _Pragma("unroll")                                                      \
      for (int i = 0; i < 4; ++i) vA[h][i] = aP4[h][(t) * 16 + i];           \
  } while (0)
#define ISSUE_B(t) do {                                                      \
    _Pragma("unroll")                                                        \
    for (int h = 0; h < 2; ++h)                                              \
      _Pragma("unroll")                                                      \
      for (int q = 0; q < 2; ++q) vB[h][q] = bP4[h][(t) * 8 + q];            \
  } while (0)
#define CVT_WRITE_A(vreg, arr) do {                                          \
    bf16x8 lo, hi;                                                           \
    lo[0] = (__bf16)vreg[0].x; lo[1] = (__bf16)vreg[0].y;                    \
    lo[2] = (__bf16)vreg[0].z; lo[3] = (__bf16)vreg[0].w;                    \
    lo[4] = (__bf16)vreg[1].x; lo[5] = (__bf16)vreg[1].y;                    \
    lo[6] = (__bf16)vreg[1].z; lo[7] = (__bf16)vreg[1].w;                    \
    hi[0] = (__bf16)vreg[2].x; hi[1] = (__bf16)vreg[2].y;                    \
    hi[2] = (__bf16)vreg[2].z; hi[3] = (__bf16)vreg[2].w;                    \
    hi[4] = (__bf16)vreg[3].x; hi[5] = (__bf16)vreg[3].y;                    \
    hi[6] = (__bf16)vreg[3].z; hi[7] = (__bf16)vreg[3].w;                    \
    *reinterpret_cast<bf16x8*>(&arr[wr0]) = lo;                              \
    *reinterpret_cast<bf16x8*>(&arr[wr1]) = hi;                              \
  } while (0)
#define WR_A(arr0, arr1) do { CVT_WRITE_A(vA[0], arr0); CVT_WRITE_A(vA[1], arr1); } while (0)
#define WR_B(arr0, arr1) do {                                                \
    *reinterpret_cast<uint4*>(&arr0[wr0]) = vB[0][0];                        \
    *reinterpret_cast<uint4*>(&arr0[wr1]) = vB[0][1];                        \
    *reinterpret_cast<uint4*>(&arr1[wr0]) = vB[1][0];                        \
    *reinterpret_cast<uint4*>(&arr1[wr1]) = vB[1][1];                        \
  } while (0)

  // ---- prologue: stage tile 0 into the E slot (one exposed load latency)
  ISSUE_A(0);
  ISSUE_B(0);
  WR_A(sA_e0, sA_e1);
  WR_B(sB_e0, sB_e1);
  asm volatile("s_waitcnt lgkmcnt(0)" ::: "memory");
  BAR();

  const int fr  = lane & 15;   // fragment m/n index
  const int fkc = lane >> 4;   // fragment k-chunk (0..3)
  const int sw  = fr & 7;      // read-side XOR (== row&7)

  f32x4 acc[2][2][4][2];
#pragma unroll
  for (int a = 0; a < 2; ++a)
#pragma unroll
    for (int bq = 0; bq < 2; ++bq)
#pragma unroll
      for (int im = 0; im < 4; ++im)
#pragma unroll
        for (int in = 0; in < 2; ++in)
          acc[a][bq][im][in] = (f32x4){0.f, 0.f, 0.f, 0.f};

  bf16x8 af[4][2], bf0[2][2], bf1[2][2];

#define LD_A(arr)                                                            \
  _Pragma("unroll")                                                          \
  for (int im = 0; im < 4; ++im)                                             \
    _Pragma("unroll")                                                        \
    for (int kk = 0; kk < 2; ++kk)                                           \
      af[im][kk] = *(const bf16x8*)&arr[(size_t)(rw * 64 + im * 16 + fr) * 64 \
                                        + (((kk * 4 + fkc) ^ sw) * 8)];
#define LD_B(arr, dst)                                                       \
  _Pragma("unroll")                                                          \
  for (int in = 0; in < 2; ++in)                                             \
    _Pragma("unroll")                                                        \
    for (int kk = 0; kk < 2; ++kk)                                           \
      dst[in][kk] = *(const bf16x8*)&arr[(size_t)(cw * 32 + in * 16 + fr) * 64 \
                                         + (((kk * 4 + fkc) ^ sw) * 8)];
#define MFMA16(aq, bq_, B_)                                                  \
  __builtin_amdgcn_s_setprio(1);                                             \
  _Pragma("unroll")                                                          \
  for (int im = 0; im < 4; ++im)                                             \
    _Pragma("unroll")                                                        \
    for (int in = 0; in < 2; ++in)                                           \
      _Pragma("unroll")                                                      \
      for (int kk = 0; kk < 2; ++kk)                                         \
        acc[aq][bq_][im][in] = __builtin_amdgcn_mfma_f32_16x16x32_bf16(      \
            af[im][kk], B_[in][kk], acc[aq][bq_][im][in], 0, 0, 0);          \
  __builtin_amdgcn_s_setprio(0);

  for (int it = 0; it < KT / 2; ++it) {
    const bool g = (it < 7);

    // ========== even tile t = 2*it (read E slot; stage t+1 -> O) ==========
    // p0: quadrant (0,0); issue A+B(t+1) loads (2-phase landing window)
    LD_A(sA_e0);
    LD_B(sB_e0, bf0);
    ISSUE_A(2 * it + 1);
    ISSUE_B(2 * it + 1);
    BAR();
    MFMA16(0, 0, bf0);
    BAR();
    // p1: quadrant (0,1)
    LD_B(sB_e1, bf1);
    BAR();
    MFMA16(0, 1, bf1);
    BAR();
    // p2: quadrant (1,1); cvt+write staged tile into O slot
    LD_A(sA_e1);
    WR_A(sA_o0, sA_o1);
    WR_B(sB_o0, sB_o1);
    BAR();
    MFMA16(1, 1, bf1);
    BAR();
    // p3: quadrant (1,0); bf0 RELOADED (not held) — frees 32 frag regs
    LD_B(sB_e0, bf0);
    BAR();
    MFMA16(1, 0, bf0);
    asm volatile("s_waitcnt lgkmcnt(0)" ::: "memory");  // publish O slot
    BAR();

    // ========== odd tile t = 2*it+1 (read O slot; stage t+1 -> E) =========
    // p0: quadrant (0,0)
    LD_A(sA_o0);
    LD_B(sB_o0, bf0);
    if (g) { ISSUE_A(2 * it + 2); ISSUE_B(2 * it + 2); }
    BAR();
    MFMA16(0, 0, bf0);
    BAR();
    // p1: quadrant (0,1)
    LD_B(sB_o1, bf1);
    BAR();
    MFMA16(0, 1, bf1);
    BAR();
    // p2: quadrant (1,1)
    LD_A(sA_o1);
    if (g) { WR_A(sA_e0, sA_e1); WR_B(sB_e0, sB_e1); }
    BAR();
    MFMA16(1, 1, bf1);
    BAR();
    // p3: quadrant (1,0)
    LD_B(sB_o0, bf0);
    BAR();
    MFMA16(1, 0, bf0);
    asm volatile("s_waitcnt lgkmcnt(0)" ::: "memory");
    BAR();
  }
#undef ISSUE_A
#undef ISSUE_B
#undef CVT_WRITE_A
#undef WR_A
#undef WR_B
#undef LD_A
#undef LD_B
#undef MFMA16

  // Epilogue. C/D layout (verified m89/m91): col = lane&15, row = (lane>>4)*4 + reg.
  const int crow0 = (lane >> 4) * 4;
  float* outBase = out + (size_t)be * (Cdim * Odim)
                 + (size_t)(mt * 256) * Odim + nt * 256;
#pragma unroll
  for (int a = 0; a < 2; ++a)
#pragma unroll
    for (int im = 0; im < 4; ++im) {
      float* prow = outBase + (size_t)(a * 128 + rw * 64 + im * 16 + crow0) * Odim;
#pragma unroll
      for (int bq = 0; bq < 2; ++bq)
#pragma unroll
        for (int in = 0; in < 2; ++in) {
          const int col  = bq * 128 + cw * 32 + in * 16 + fr;
          const float bv = bias[e * Odim + nt * 256 + col];
          float* p = prow + col;
#pragma unroll
          for (int r4 = 0; r4 < 4; ++r4)
            p[(size_t)r4 * Odim] = acc[a][bq][im][in][r4] + bv;
        }
    }
}

extern "C" void kernel_launch(void* const* d_in, const int* in_sizes, int n_in,
                              void* d_out, int out_size, void* d_ws, size_t ws_size,
                              hipStream_t stream) {
  const float* x = (const float*)d_in[0];       // (B,T,D) f32
  const int* idx = (const int*)d_in[1];         // (B,E,C) i32
  const float* w = (const float*)d_in[2];       // (E,O,D) f32
  const float* bias = (const float*)d_in[3];    // (E,O) f32
  float* out = (float*)d_out;

  // Workspace: w_bf16 (8 MiB)
  unsigned short* wbf = (unsigned short*)d_ws;

  const int nw4 = Edim * Odim * Ddim / 4;  // 1,048,576
  cast_w<<<(nw4 + 255) / 256, 256, 0, stream>>>(w, wbf, nw4);

  // 32 (b,e) pairs x 4 M-tiles x 2 N-tiles = 256 blocks (1/CU), XCD-swizzled
  moe_mfma_gemm<<<256, 512, 0, stream>>>(x, idx, wbf, bias, out);
}

// Round 6
// 167.688 us; speedup vs baseline: 1.7716x; 1.2353x over previous
//
#include <hip/hip_runtime.h>
#include <stdint.h>

// Problem constants (reference: B,T,D=4,4096,1024; E,C,O=8,1024,512)
#define Bdim 4
#define Tdim 4096
#define Ddim 1024
#define Edim 8
#define Cdim 1024
#define Odim 512
#define KT 16           // K tiles of 64 (Ddim/64)
#define PAN 16384       // ushorts per K-panel: 256 rows * 64 elems

using bf16x8 = __attribute__((ext_vector_type(8))) __bf16;
using f32x4  = __attribute__((ext_vector_type(4))) float;
using u16x8  = __attribute__((ext_vector_type(8))) unsigned short;

// round-to-nearest-even f32 -> bf16
__device__ __forceinline__ unsigned short f2bf(float f) {
  unsigned int u = __float_as_uint(f);
  u += 0x7fffu + ((u >> 16) & 1u);
  return (unsigned short)(u >> 16);
}

// W-panel prep (tiny: ~48MB traffic): W'[e][nt][kt][256][64] bf16, row r
// slot c holds global k-chunk (c ^ (r&7)) — XOR pre-swizzle baked so GEMM
// B-staging DMA is contiguous 1KB/instr (R7-proven layout, W part only).
__global__ void cast_w_panel(const float* __restrict__ w,
                             unsigned short* __restrict__ Wp, int nW) {
  const int j = blockIdx.x * blockDim.x + threadIdx.x;
  if (j >= nW) return;
  const int c  = j & 7;
  const int r  = (j >> 3) & 255;
  const int kt = (j >> 11) & 15;
  const int nt = (j >> 15) & 1;
  const int e  = j >> 16;
  const float* src = w + ((size_t)(e * Odim + nt * 256 + r)) * Ddim + kt * 64 +
                     ((c ^ (r & 7)) * 8);
  const float4 v0 = reinterpret_cast<const float4*>(src)[0];
  const float4 v1 = reinterpret_cast<const float4*>(src)[1];
  u16x8 o;
  o[0] = f2bf(v0.x); o[1] = f2bf(v0.y); o[2] = f2bf(v0.z); o[3] = f2bf(v0.w);
  o[4] = f2bf(v1.x); o[5] = f2bf(v1.y); o[6] = f2bf(v1.z); o[7] = f2bf(v1.w);
  *reinterpret_cast<u16x8*>(Wp + (size_t)j * 8) = o;
}

// async global->LDS, 16B per lane; LDS dest is wave-uniform base.
__device__ __forceinline__ void async_copy16(const unsigned short* g,
                                             unsigned short* l) {
  __builtin_amdgcn_global_load_lds(
      (__attribute__((address_space(1))) unsigned int*)g,
      (__attribute__((address_space(3))) unsigned int*)l, 16, 0, 0);
}

#define FENCE() asm volatile("" ::: "memory")
#define BAR()   do { FENCE(); __builtin_amdgcn_s_barrier(); FENCE(); } while (0)

// R10 hybrid fusion: x-cast deleted (A reg-staged f32 gather + cvt + swizzled
// ds_write, 32 staging VGPR); B via global_load_lds from pre-swizzled bf16
// panels (0 staging regs) — fixes R8/R9 spill (A+B reg-staging needed ~145
// arch VGPR beside the 128-AGPR acc; only 128 available).
// Skeleton = R6/R7: 256x256, 8 waves, 4 quadrant-phases/K-tile, T5 setprio,
// T2 swizzle, T1 XCD swizzle, 8 static LDS arrays double-buffered E/O.
// Per even tile (read E, stage t+1 -> O):
//   p0: LD_A(e0)+LD_B(e0); issue A(t+1) f32 loads; DMA B(t+1) half0 -> o0
//   p1: LD_B(e1);          DMA B(t+1) half1 -> o1
//   p2: LD_A(e1); cvt+ds_write A(t+1) -> o0/o1 (compiler waits A-loads only:
//       they are the 8 OLDEST vmem ops, younger B-DMAs keep flying)
//   p3: reload bf0 from e0 (frag-pressure relief); MFMA; vmcnt(0)+lgkmcnt(0)
//       publish (B-DMAs are 2-3 phases old -> near-free drain)
__global__ __launch_bounds__(512) void moe_mfma_gemm(
    const float* __restrict__ x,             // (B,T,D) f32
    const int* __restrict__ idx,             // (B,E,C)
    const unsigned short* __restrict__ Wpan, // pre-swizzled W panels (bf16)
    const float* __restrict__ bias,          // (E,O)
    float* __restrict__ out) {               // (B,E,C,O) f32
  __shared__ __align__(16) unsigned short sA_e0[128 * 64];
  __shared__ __align__(16) unsigned short sA_e1[128 * 64];
  __shared__ __align__(16) unsigned short sA_o0[128 * 64];
  __shared__ __align__(16) unsigned short sA_o1[128 * 64];
  __shared__ __align__(16) unsigned short sB_e0[128 * 64];
  __shared__ __align__(16) unsigned short sB_e1[128 * 64];
  __shared__ __align__(16) unsigned short sB_o0[128 * 64];
  __shared__ __align__(16) unsigned short sB_o1[128 * 64];

  // XCD-aware decode: e fastest (XCD = e). 256 blocks = 1/CU.
  const int bid = blockIdx.x;
  const int e   = bid & 7;
  const int rr_ = bid >> 3;       // 0..31
  const int nt  = rr_ & 1;        // N tile (256 cols)
  const int mt  = (rr_ >> 1) & 3; // M tile (256 rows)
  const int bb  = rr_ >> 3;       // batch
  const int be  = bb * Edim + e;

  const int tid  = threadIdx.x;
  const int lane = tid & 63;
  const int wid  = tid >> 6;   // 0..7
  const int rw   = wid >> 2;   // 0..1: 64-row sub-block within the A half
  const int cw   = wid & 3;    // 0..3: 32-col sub-block within the B half

  // ---- A staging geometry (reg path): lane owns row rloc = wid*16+(lane>>2)
  // of each 128-row half and f32 elems [(lane&3)*16, +16) of the K-tile.
  const int rloc = wid * 16 + (lane >> 2);   // 0..127
  const int csub = (lane & 3) * 16;

  const float4* aP4[2];
#pragma unroll
  for (int h = 0; h < 2; ++h) {
    const int tok = idx[be * Cdim + mt * 256 + h * 128 + rloc];
    aP4[h] = reinterpret_cast<const float4*>(
        x + (size_t)(bb * Tdim + tok) * Ddim + csub);
  }
  // ---- B staging geometry (DMA path): contiguous panel rows.
  const unsigned short* Bbase = Wpan + ((size_t)(e * 2 + nt) * KT) * PAN;
  const int lo = lane * 8;  // lane's 16B within the wave's 1KB segment

  const int wr0 = rloc * 64 + (((lane & 3) * 2) ^ (rloc & 7)) * 8;      // lo chunk
  const int wr1 = rloc * 64 + (((lane & 3) * 2 + 1) ^ (rloc & 7)) * 8;  // hi chunk

  float4 vA[2][4];

#define ISSUE_A(t) do {                                                      \
    _Pragma("unroll")                                                        \
    for (int h = 0; h < 2; ++h)                                              \
      _Pragma("unroll")                                                      \
      for (int i = 0; i < 4; ++i) vA[h][i] = aP4[h][(t) * 16 + i];           \
  } while (0)
#define DMA_B(h, dstArr, kt) do {                                            \
    async_copy16(Bbase + (size_t)(kt) * PAN + ((h) * 128 + wid * 16) * 64 + lo, \
                 &dstArr[wid * 16 * 64]);                                    \
    async_copy16(Bbase + (size_t)(kt) * PAN + ((h) * 128 + wid * 16 + 8) * 64 + lo, \
                 &dstArr[(wid * 16 + 8) * 64]);                              \
  } while (0)
#define CVT_WRITE_A(vreg, arr) do {                                          \
    bf16x8 lov, hiv;                                                         \
    lov[0] = (__bf16)vreg[0].x; lov[1] = (__bf16)vreg[0].y;                  \
    lov[2] = (__bf16)vreg[0].z; lov[3] = (__bf16)vreg[0].w;                  \
    lov[4] = (__bf16)vreg[1].x; lov[5] = (__bf16)vreg[1].y;                  \
    lov[6] = (__bf16)vreg[1].z; lov[7] = (__bf16)vreg[1].w;                  \
    hiv[0] = (__bf16)vreg[2].x; hiv[1] = (__bf16)vreg[2].y;                  \
    hiv[2] = (__bf16)vreg[2].z; hiv[3] = (__bf16)vreg[2].w;                  \
    hiv[4] = (__bf16)vreg[3].x; hiv[5] = (__bf16)vreg[3].y;                  \
    hiv[6] = (__bf16)vreg[3].z; hiv[7] = (__bf16)vreg[3].w;                  \
    *reinterpret_cast<bf16x8*>(&arr[wr0]) = lov;                             \
    *reinterpret_cast<bf16x8*>(&arr[wr1]) = hiv;                             \
  } while (0)
#define WR_A(arr0, arr1) do { CVT_WRITE_A(vA[0], arr0); CVT_WRITE_A(vA[1], arr1); } while (0)

  // ---- prologue: stage tile 0 into the E slot (one exposed load latency)
  ISSUE_A(0);
  DMA_B(0, sB_e0, 0);
  DMA_B(1, sB_e1, 0);
  WR_A(sA_e0, sA_e1);  // compiler waits the 8 A-loads here
  asm volatile("s_waitcnt vmcnt(0) lgkmcnt(0)" ::: "memory");
  BAR();

  const int fr  = lane & 15;   // fragment m/n index
  const int fkc = lane >> 4;   // fragment k-chunk (0..3)
  const int sw  = fr & 7;      // read-side XOR (== row&7)

  f32x4 acc[2][2][4][2];
#pragma unroll
  for (int a = 0; a < 2; ++a)
#pragma unroll
    for (int bq = 0; bq < 2; ++bq)
#pragma unroll
      for (int im = 0; im < 4; ++im)
#pragma unroll
        for (int in = 0; in < 2; ++in)
          acc[a][bq][im][in] = (f32x4){0.f, 0.f, 0.f, 0.f};

  bf16x8 af[4][2], bf0[2][2], bf1[2][2];

#define LD_A(arr)                                                            \
  _Pragma("unroll")                                                          \
  for (int im = 0; im < 4; ++im)                                             \
    _Pragma("unroll")                                                        \
    for (int kk = 0; kk < 2; ++kk)                                           \
      af[im][kk] = *(const bf16x8*)&arr[(size_t)(rw * 64 + im * 16 + fr) * 64 \
                                        + (((kk * 4 + fkc) ^ sw) * 8)];
#define LD_B(arr, dst)                                                       \
  _Pragma("unroll")                                                          \
  for (int in = 0; in < 2; ++in)                                             \
    _Pragma("unroll")                                                        \
    for (int kk = 0; kk < 2; ++kk)                                           \
      dst[in][kk] = *(const bf16x8*)&arr[(size_t)(cw * 32 + in * 16 + fr) * 64 \
                                         + (((kk * 4 + fkc) ^ sw) * 8)];
#define MFMA16(aq, bq_, B_)                                                  \
  __builtin_amdgcn_s_setprio(1);                                             \
  _Pragma("unroll")                                                          \
  for (int im = 0; im < 4; ++im)                                             \
    _Pragma("unroll")                                                        \
    for (int in = 0; in < 2; ++in)                                           \
      _Pragma("unroll")                                                      \
      for (int kk = 0; kk < 2; ++kk)                                         \
        acc[aq][bq_][im][in] = __builtin_amdgcn_mfma_f32_16x16x32_bf16(      \
            af[im][kk], B_[in][kk], acc[aq][bq_][im][in], 0, 0, 0);          \
  __builtin_amdgcn_s_setprio(0);

  for (int it = 0; it < KT / 2; ++it) {
    const bool g = (it < 7);

    // ========== even tile t = 2*it (read E; stage t+1 -> O) ==========
    // p0: quadrant (0,0); issue A(t+1) regs + DMA B(t+1) half0
    LD_A(sA_e0);
    LD_B(sB_e0, bf0);
    ISSUE_A(2 * it + 1);
    DMA_B(0, sB_o0, 2 * it + 1);
    BAR();
    MFMA16(0, 0, bf0);
    BAR();
    // p1: quadrant (0,1); DMA B(t+1) half1
    LD_B(sB_e1, bf1);
    DMA_B(1, sB_o1, 2 * it + 1);
    BAR();
    MFMA16(0, 1, bf1);
    BAR();
    // p2: quadrant (1,1); cvt+write A(t+1) -> O
    LD_A(sA_e1);
    WR_A(sA_o0, sA_o1);
    BAR();
    MFMA16(1, 1, bf1);
    BAR();
    // p3: quadrant (1,0); bf0 reloaded (frag-pressure relief); publish O
    LD_B(sB_e0, bf0);
    BAR();
    MFMA16(1, 0, bf0);
    asm volatile("s_waitcnt vmcnt(0) lgkmcnt(0)" ::: "memory");
    BAR();

    // ========== odd tile t = 2*it+1 (read O; stage t+1 -> E) =========
    // p0: quadrant (0,0)
    LD_A(sA_o0);
    LD_B(sB_o0, bf0);
    if (g) { ISSUE_A(2 * it + 2); DMA_B(0, sB_e0, 2 * it + 2); }
    BAR();
    MFMA16(0, 0, bf0);
    BAR();
    // p1: quadrant (0,1)
    LD_B(sB_o1, bf1);
    if (g) DMA_B(1, sB_e1, 2 * it + 2);
    BAR();
    MFMA16(0, 1, bf1);
    BAR();
    // p2: quadrant (1,1)
    LD_A(sA_o1);
    if (g) WR_A(sA_e0, sA_e1);
    BAR();
    MFMA16(1, 1, bf1);
    BAR();
    // p3: quadrant (1,0); publish E
    LD_B(sB_o0, bf0);
    BAR();
    MFMA16(1, 0, bf0);
    asm volatile("s_waitcnt vmcnt(0) lgkmcnt(0)" ::: "memory");
    BAR();
  }
#undef ISSUE_A
#undef DMA_B
#undef CVT_WRITE_A
#undef WR_A
#undef LD_A
#undef LD_B
#undef MFMA16

  // Epilogue. C/D layout (verified m89/m91): col = lane&15, row = (lane>>4)*4 + reg.
  const int crow0 = (lane >> 4) * 4;
  float* outBase = out + (size_t)be * (Cdim * Odim)
                 + (size_t)(mt * 256) * Odim + nt * 256;
#pragma unroll
  for (int a = 0; a < 2; ++a)
#pragma unroll
    for (int im = 0; im < 4; ++im) {
      float* prow = outBase + (size_t)(a * 128 + rw * 64 + im * 16 + crow0) * Odim;
#pragma unroll
      for (int bq = 0; bq < 2; ++bq)
#pragma unroll
        for (int in = 0; in < 2; ++in) {
          const int col  = bq * 128 + cw * 32 + in * 16 + fr;
          const float bv = bias[e * Odim + nt * 256 + col];
          float* p = prow + col;
#pragma unroll
          for (int r4 = 0; r4 < 4; ++r4)
            p[(size_t)r4 * Odim] = acc[a][bq][im][in][r4] + bv;
        }
    }
}

extern "C" void kernel_launch(void* const* d_in, const int* in_sizes, int n_in,
                              void* d_out, int out_size, void* d_ws, size_t ws_size,
                              hipStream_t stream) {
  const float* x = (const float*)d_in[0];       // (B,T,D) f32
  const int* idx = (const int*)d_in[1];         // (B,E,C) i32
  const float* w = (const float*)d_in[2];       // (E,O,D) f32
  const float* bias = (const float*)d_in[3];    // (E,O) f32
  float* out = (float*)d_out;

  // Workspace: W panels (8 MiB)
  unsigned short* Wp = (unsigned short*)d_ws;

  const int nW = Edim * Odim * (Ddim / 8);  // 524,288 chunks
  cast_w_panel<<<(nW + 255) / 256, 256, 0, stream>>>(w, Wp, nW);

  // 32 (b,e) pairs x 4 M-tiles x 2 N-tiles = 256 blocks (1/CU), XCD-swizzled
  moe_mfma_gemm<<<256, 512, 0, stream>>>(x, idx, Wp, bias, out);
}